// Round 5
// baseline (397.768 us; speedup 1.0000x reference)
//
#include <hip/hip_runtime.h>

#define TT 512
#define DD 16
#define HH 30
#define LL 10
#define C  4                  // timesteps per phase (chunk)
#define TCH (TT / C)          // 128 chunks
#define PH (TCH + LL - 1)     // 137 phases
#define ROWH 40               // halfs per row (80 B): [data 0..31 | pad]
#define WAVES 5
#define BLOCKT (WAVES * 64)   // 320 threads

typedef _Float16 h2 __attribute__((ext_vector_type(2)));

__device__ __forceinline__ float tanh_fast(float x) {
    // tanh(x) = 1 - 2/(exp(2x)+1); saturates correctly at +-inf
    float e = __expf(2.0f * x);
    return 1.0f - 2.0f * __builtin_amdgcn_rcpf(e + 1.0f);
}

#if __has_builtin(__builtin_amdgcn_fdot2)
#define DOT2(a, b, c) __builtin_amdgcn_fdot2((a), (b), (c), false)
#else
__device__ __forceinline__ float DOT2(h2 a, h2 b, float c) {
    return fmaf((float)a.x, (float)b.x, fmaf((float)a.y, (float)b.y, c));
}
#endif

__device__ __forceinline__ h2 asH2(unsigned u) {
    union { unsigned u; h2 h; } v; v.u = u; return v.h;
}

// One neuron-timestep: 16 dot2 over this lane-half's 32-half source row,
// cross-half combine, tanh. (half0: in-row, bias; half1: own-row, 0)
__device__ __forceinline__ float layer_step(const _Float16* __restrict__ src,
                                            const h2* __restrict__ w,
                                            float binit)
{
    const uint4* s4 = (const uint4*)src;
    const uint4 r0 = s4[0], r1 = s4[1], r2 = s4[2], r3 = s4[3];
    const unsigned wv[16] = { r0.x,r0.y,r0.z,r0.w, r1.x,r1.y,r1.z,r1.w,
                              r2.x,r2.y,r2.z,r2.w, r3.x,r3.y,r3.z,r3.w };
    float a = binit;
    #pragma unroll
    for (int c = 0; c < 16; ++c)
        a = DOT2(w[c], asH2(wv[c]), a);
    a += __shfl_xor(a, 32);         // combine in-dot (half0) + own-dot (half1)
    return tanh_fast(a);
}

__global__ __launch_bounds__(BLOCKT, 5) void rnn_split(
    const float* __restrict__ x,   const float* __restrict__ wi0,
    const float* __restrict__ wih, const float* __restrict__ whh,
    const float* __restrict__ bih, const float* __restrict__ bhh,
    const float* __restrict__ fcw, const float* __restrict__ fcb,
    float* __restrict__ out)
{
    // act[parity][layer][cc]: INPUT row for layer at chunk-step cc
    //   (halfs 0..31 data: layer0 = x(16)+pad, else h(30)+pad; rest pad).
    // own[layer]: layer's own h (same-wave producer/consumer, no parity).
    __shared__ __align__(16) _Float16 act[2][LL][C][ROWH];   // 6400 B
    __shared__ __align__(16) _Float16 own[LL][ROWH];         //  800 B

    const int tid  = threadIdx.x;
    const int w    = tid >> 6;        // wave 0..4
    const int lane = tid & 63;
    const int half = lane >> 5;       // 0: input-dot, 1: own-dot
    const int g    = lane & 31;       // neuron (g<30 active)
    const int gm   = (g < HH) ? g : HH - 1;
    const int batch = blockIdx.x;

    const int lA = w;                 // this wave's layers
    const int lB = w + WAVES;

    // ---- weights: 16 h2 words per layer; half0 = in-row, half1 = own-row ----
    h2 wA[16], wB[16];
    #pragma unroll
    for (int c = 0; c < 16; ++c) {
        const int k0 = 2 * c, k1 = 2 * c + 1;
        float a0 = 0.f, a1 = 0.f, b0 = 0.f, b1 = 0.f;
        if (half == 0) {
            if (lA == 0) {
                if (k0 < DD) a0 = wi0[gm * DD + k0];
                if (k1 < DD) a1 = wi0[gm * DD + k1];
            } else {
                if (k0 < HH) a0 = wih[(lA - 1) * 900 + gm * HH + k0];
                if (k1 < HH) a1 = wih[(lA - 1) * 900 + gm * HH + k1];
            }
            if (k0 < HH) b0 = wih[(lB - 1) * 900 + gm * HH + k0];  // lB >= 5
            if (k1 < HH) b1 = wih[(lB - 1) * 900 + gm * HH + k1];
        } else {
            if (k0 < HH) { a0 = whh[lA * 900 + gm * HH + k0];
                           b0 = whh[lB * 900 + gm * HH + k0]; }
            if (k1 < HH) { a1 = whh[lA * 900 + gm * HH + k1];
                           b1 = whh[lB * 900 + gm * HH + k1]; }
        }
        wA[c] = h2{(_Float16)a0, (_Float16)a1};
        wB[c] = h2{(_Float16)b0, (_Float16)b1};
    }
    // bias folded once (half0 only; half1 contributes 0 before combine)
    const float bcA = (half == 0) ? bih[lA * HH + gm] + bhh[lA * HH + gm] : 0.f;
    const float bcB = (half == 0) ? bih[lB * HH + gm] + bhh[lB * HH + gm] : 0.f;
    float fw = 0.f, fbv = 0.f;
    if (w == WAVES - 1) { fw = (g < HH) ? fcw[g] : 0.f; fbv = fcb[0]; }

    // ---- zero LDS (pads must stay true zero; h(-1)=0) ----
    {
        unsigned* za = (unsigned*)&act[0][0][0][0];
        for (int i = tid; i < (int)(sizeof(act) / 4); i += BLOCKT) za[i] = 0u;
        unsigned* zo = (unsigned*)&own[0][0];
        for (int i = tid; i < (int)(sizeof(own) / 4); i += BLOCKT) zo[i] = 0u;
    }
    __syncthreads();

    // ---- x staging (wave 0, lanes<32): sc = chunk-step, sq = float2 quarter ----
    const int sq = lane & 7;
    const int sc = (lane >> 3) & 3;
    const float2* xb2 = (const float2*)x + (size_t)batch * (TT * DD / 2);
    if (w == 0 && lane < 32) {
        float2 v = xb2[sc * (DD / 2) + sq];   // chunk 0: t = sc
        *(h2*)&act[1][0][sc][2 * sq] = h2{(_Float16)v.x, (_Float16)v.y};
    }

    float hl = 0.f;                  // wave 4 keeps h_9(T-1) for FC

    for (int p = 0; p < PH; ++p) {
        const int q  = (p + 1) & 1;  // read parity
        const int wp = p & 1;        // write parity

        // wave 0: issue next chunk's x loads early (hidden under compute)
        float2 xv;
        const bool dost = (w == 0) && (lane < 32) && (p + 1 < TCH);
        if (dost)
            xv = xb2[((p + 1) * C + sc) * (DD / 2) + sq];

        // ---- layer A ----
        const int ptA = p - lA;
        if (0 <= ptA && ptA < TCH) {
            #pragma unroll
            for (int cc = 0; cc < C; ++cc) {
                const _Float16* src = half ? &own[lA][0] : &act[q][lA][cc][0];
                const float h = layer_step(src, wA, bcA);
                const _Float16 hh = (_Float16)h;
                if (g < HH) {
                    if (half == 0)        own[lA][g] = hh;           // t+1 self
                    else                  act[wp][lA + 1][cc][g] = hh; // lA<=4
                }
            }
        }

        // ---- layer B ----
        const int ptB = p - lB;
        if (0 <= ptB && ptB < TCH) {
            #pragma unroll
            for (int cc = 0; cc < C; ++cc) {
                const _Float16* src = half ? &own[lB][0] : &act[q][lB][cc][0];
                const float h = layer_step(src, wB, bcB);
                const _Float16 hh = (_Float16)h;
                if (g < HH) {
                    if (half == 0)        own[lB][g] = hh;
                    else if (lB < LL - 1) act[wp][lB + 1][cc][g] = hh;
                }
                if (lB == LL - 1) hl = h;
            }
        }

        // wave 0: convert + write staged x rows for next chunk
        if (dost)
            *(h2*)&act[wp][0][sc][2 * sq] = h2{(_Float16)xv.x, (_Float16)xv.y};

        __syncthreads();
    }

    // ---- FC on h_9(T-1): out[b] = fcw . h + fcb ----
    if (w == WAVES - 1) {
        float v = (g < HH) ? hl * fw : 0.f;   // both halves hold identical h
        v += __shfl_xor(v, 1);
        v += __shfl_xor(v, 2);
        v += __shfl_xor(v, 4);
        v += __shfl_xor(v, 8);
        v += __shfl_xor(v, 16);               // per-half sum == full sum
        if (lane == 0) out[batch] = v + fbv;
    }
}

extern "C" void kernel_launch(void* const* d_in, const int* in_sizes, int n_in,
                              void* d_out, int out_size, void* d_ws, size_t ws_size,
                              hipStream_t stream) {
    const float* x   = (const float*)d_in[0];
    const float* wi0 = (const float*)d_in[1];
    const float* wih = (const float*)d_in[2];
    const float* whh = (const float*)d_in[3];
    const float* bih = (const float*)d_in[4];
    const float* bhh = (const float*)d_in[5];
    const float* fcw = (const float*)d_in[6];
    const float* fcb = (const float*)d_in[7];
    float* out = (float*)d_out;

    rnn_split<<<1024, BLOCKT, 0, stream>>>(x, wi0, wih, whh, bih, bhh,
                                           fcw, fcb, out);
}

// Round 6
// 335.075 us; speedup vs baseline: 1.1871x; 1.1871x over previous
//
#include <hip/hip_runtime.h>

#define TT 512
#define DD 16
#define HH 30
#define LL 10
#define C  8                  // timesteps per phase (chunk)
#define TCH (TT / C)          // 64 chunks
#define PH (TCH + LL - 1)     // 73 phases
#define ROWH 40               // halfs per row (80 B): [data 0..31 | pad]
#define WAVES 5
#define BLOCKT (WAVES * 64)   // 320 threads

typedef _Float16 h2 __attribute__((ext_vector_type(2)));

__device__ __forceinline__ float tanh_fast(float x) {
    // tanh(x) = 1 - 2/(exp(2x)+1); saturates correctly at +-inf
    float e = __expf(2.0f * x);
    return 1.0f - 2.0f * __builtin_amdgcn_rcpf(e + 1.0f);
}

#if __has_builtin(__builtin_amdgcn_fdot2)
#define DOT2(a, b, c) __builtin_amdgcn_fdot2((a), (b), (c), false)
#else
__device__ __forceinline__ float DOT2(h2 a, h2 b, float c) {
    return fmaf((float)a.x, (float)b.x, fmaf((float)a.y, (float)b.y, c));
}
#endif

__device__ __forceinline__ h2 asH2(unsigned u) {
    union { unsigned u; h2 h; } v; v.u = u; return v.h;
}

__global__ __launch_bounds__(BLOCKT, 5) void rnn_dual(
    const float* __restrict__ x,   const float* __restrict__ wi0,
    const float* __restrict__ wih, const float* __restrict__ whh,
    const float* __restrict__ bih, const float* __restrict__ bhh,
    const float* __restrict__ fcw, const float* __restrict__ fcb,
    float* __restrict__ out)
{
    // act[parity][layer][cc]: INPUT row for layer at chunk-step cc
    //   (halfs 0..31 data: layer0 = x(16)+pad, else h(30)+pad; rest pad).
    // own[layer]: layer's own h (same-half producer/consumer, no parity).
    __shared__ __align__(16) _Float16 act[2][LL][C][ROWH];   // 12800 B
    __shared__ __align__(16) _Float16 own[LL][ROWH];         //   800 B

    const int tid  = threadIdx.x;
    const int w    = tid >> 6;        // wave 0..4
    const int lane = tid & 63;
    const int half = lane >> 5;       // 0: layer w, 1: layer w+5
    const int g    = lane & 31;       // neuron (g<30 active)
    const int gm   = (g < HH) ? g : HH - 1;
    const int batch = blockIdx.x;
    const int myl  = w + half * WAVES;   // this half-wave's layer, 0..9

    // ---- weights row gm of layer myl: words 0..15 = input, 16..31 = own ----
    h2 wr[32];
    #pragma unroll
    for (int c = 0; c < 16; ++c) {
        const int k0 = 2 * c, k1 = 2 * c + 1;
        float a0 = 0.f, a1 = 0.f;
        if (myl == 0) {
            if (k0 < DD) a0 = wi0[gm * DD + k0];
            if (k1 < DD) a1 = wi0[gm * DD + k1];
        } else {
            if (k0 < HH) a0 = wih[(myl - 1) * 900 + gm * HH + k0];
            if (k1 < HH) a1 = wih[(myl - 1) * 900 + gm * HH + k1];
        }
        wr[c] = h2{(_Float16)a0, (_Float16)a1};
    }
    #pragma unroll
    for (int c = 0; c < 16; ++c) {
        const int k0 = 2 * c, k1 = 2 * c + 1;
        float a0 = 0.f, a1 = 0.f;
        if (k0 < HH) a0 = whh[myl * 900 + gm * HH + k0];
        if (k1 < HH) a1 = whh[myl * 900 + gm * HH + k1];
        wr[16 + c] = h2{(_Float16)a0, (_Float16)a1};
    }
    const float bc = bih[myl * HH + gm] + bhh[myl * HH + gm];
    float fw = 0.f, fbv = 0.f;
    if (myl == LL - 1) { fw = (g < HH) ? fcw[g] : 0.f; fbv = fcb[0]; }

    // ---- zero LDS (pads must stay true zero; h(-1)=0) ----
    {
        unsigned* za = (unsigned*)&act[0][0][0][0];
        for (int i = tid; i < (int)(sizeof(act) / 4); i += BLOCKT) za[i] = 0u;
        unsigned* zo = (unsigned*)&own[0][0];
        for (int i = tid; i < (int)(sizeof(own) / 4); i += BLOCKT) zo[i] = 0u;
    }
    __syncthreads();

    // ---- x staging (wave 0, half 0): sc = chunk-step 0..7, sq = float4 quarter ----
    const int sc = g >> 2;
    const int sq = g & 3;
    const bool stager = (w == 0) && (half == 0);
    const float4* xb4 = (const float4*)x + (size_t)batch * (TT * DD / 4);

    // prestage chunk 0 (t = sc) into parity-1 rows
    if (stager) {
        float4 v = xb4[sc * (DD / 4) + sq];
        *(h2*)&act[1][0][sc][4 * sq]     = h2{(_Float16)v.x, (_Float16)v.y};
        *(h2*)&act[1][0][sc][4 * sq + 2] = h2{(_Float16)v.z, (_Float16)v.w};
    }

    float hl = 0.f;                   // layer-9 half keeps h(T-1) for FC

    for (int p = 0; p < PH; ++p) {
        const int q  = (p + 1) & 1;   // read parity
        const int wp = p & 1;         // write parity
        const int pt = p - myl;       // this half-wave's chunk index

        // stager: issue next chunk's x loads early (hidden under compute)
        float4 xv;
        const bool dost = stager && (p + 1 < TCH);
        if (dost)
            xv = xb4[((p + 1) * C + sc) * (DD / 4) + sq];

        if (0 <= pt && pt < TCH) {
            #pragma unroll
            for (int cc = 0; cc < C; ++cc) {
                const uint4* ar = (const uint4*)&act[q][myl][cc][0];
                const uint4 A = ar[0], B = ar[1], Cq = ar[2], Dq = ar[3];
                const uint4* orr = (const uint4*)&own[myl][0];
                const uint4 E = orr[0], F = orr[1], G = orr[2], Hq = orr[3];
                const unsigned win[16]  = { A.x,A.y,A.z,A.w,  B.x,B.y,B.z,B.w,
                                            Cq.x,Cq.y,Cq.z,Cq.w, Dq.x,Dq.y,Dq.z,Dq.w };
                const unsigned wown[16] = { E.x,E.y,E.z,E.w,  F.x,F.y,F.z,F.w,
                                            G.x,G.y,G.z,G.w,  Hq.x,Hq.y,Hq.z,Hq.w };
                float a0 = bc, a1 = 0.f;     // two independent 16-deep chains
                #pragma unroll
                for (int c = 0; c < 16; ++c) {
                    a0 = DOT2(wr[c],      asH2(win[c]),  a0);
                    a1 = DOT2(wr[16 + c], asH2(wown[c]), a1);
                }
                const float h = tanh_fast(a0 + a1);
                const _Float16 hh = (_Float16)h;
                if (g < HH) {
                    own[myl][g] = hh;                    // own h for t+1
                    if (myl < LL - 1)
                        act[wp][myl + 1][cc][g] = hh;    // next layer's input
                }
                hl = h;
            }
        }

        // stager: convert + write staged x rows for next chunk
        if (dost) {
            *(h2*)&act[wp][0][sc][4 * sq]     = h2{(_Float16)xv.x, (_Float16)xv.y};
            *(h2*)&act[wp][0][sc][4 * sq + 2] = h2{(_Float16)xv.z, (_Float16)xv.w};
        }

        __syncthreads();
    }

    // ---- FC on h_9(T-1): out[b] = fcw . h + fcb (layer-9 half only) ----
    if (myl == LL - 1) {
        float v = (g < HH) ? hl * fw : 0.f;
        v += __shfl_xor(v, 1);        // xor masks 1..16 stay within the half
        v += __shfl_xor(v, 2);
        v += __shfl_xor(v, 4);
        v += __shfl_xor(v, 8);
        v += __shfl_xor(v, 16);
        if (g == 0) out[batch] = v + fbv;
    }
}

extern "C" void kernel_launch(void* const* d_in, const int* in_sizes, int n_in,
                              void* d_out, int out_size, void* d_ws, size_t ws_size,
                              hipStream_t stream) {
    const float* x   = (const float*)d_in[0];
    const float* wi0 = (const float*)d_in[1];
    const float* wih = (const float*)d_in[2];
    const float* whh = (const float*)d_in[3];
    const float* bih = (const float*)d_in[4];
    const float* bhh = (const float*)d_in[5];
    const float* fcw = (const float*)d_in[6];
    const float* fcb = (const float*)d_in[7];
    float* out = (float*)d_out;

    rnn_dual<<<1024, BLOCKT, 0, stream>>>(x, wi0, wih, whh, bih, bhh,
                                          fcw, fcb, out);
}

// Round 7
// 279.918 us; speedup vs baseline: 1.4210x; 1.1970x over previous
//
#include <hip/hip_runtime.h>

#define TT 512
#define DD 16
#define HH 30
#define LL 10
#define C  4                  // timesteps per phase
#define TCH (TT / C)          // 128 chunks
#define PH (TCH + LL - 1)     // 137 phases
#define WRH 40                // halfs per batch-row (80 B): 32 data + pad
#define GRP 16                // batches per block = MFMA N
#define BLOCKT (LL * 64)      // 640 threads, wave = layer

typedef _Float16 f16x8 __attribute__((ext_vector_type(8)));
typedef _Float16 f16x4 __attribute__((ext_vector_type(4)));
typedef float    f32x4 __attribute__((ext_vector_type(4)));

union U128 { uint4 u; f16x8 h; };

// act block offset in halfs (within act region): [par][destLayer-1][cc] -> [16][WRH]
#define ACTOFF(par, lm1, cc) ((((par) * (LL - 1) + (lm1)) * C + (cc)) * (GRP * WRH))

__device__ __forceinline__ float tanh_fast(float x) {
    // tanh(x) = 1 - 2/(exp(2x)+1); saturates correctly at +-inf
    float e = __expf(2.0f * x);
    return 1.0f - 2.0f * __builtin_amdgcn_rcpf(e + 1.0f);
}

__global__ __launch_bounds__(BLOCKT) void rnn_mfma(
    const float* __restrict__ x,   const float* __restrict__ wi0,
    const float* __restrict__ wih, const float* __restrict__ whh,
    const float* __restrict__ bih, const float* __restrict__ bhh,
    const float* __restrict__ fcw, const float* __restrict__ fcb,
    float* __restrict__ out)
{
    extern __shared__ __align__(16) _Float16 sm[];
    _Float16* own = sm;                       // [LL][GRP][WRH]
    _Float16* act = sm + LL * GRP * WRH;      // [2][LL-1][C][GRP][WRH]

    const int tid  = threadIdx.x;
    const int l    = tid >> 6;        // wave == layer
    const int lane = tid & 63;
    const int n    = lane & 15;       // batch-in-group (B/D col); A m-row select
    const int qq   = lane >> 4;       // k-slice group / D row-group
    const int b0   = blockIdx.x * GRP;

    // ---- A-frags (weights). A[m][k]: m = 16*tile + (lane&15), k = 8*qq + i ----
    f16x8 wain[2], waown[2];
    #pragma unroll
    for (int tile = 0; tile < 2; ++tile) {
        const int j = 16 * tile + n;
        #pragma unroll
        for (int i = 0; i < 8; ++i) {
            const int k = 8 * qq + i;
            float vi = 0.f, vo = 0.f;
            if (j < HH) {
                if (l == 0) { if (k < DD) vi = wi0[j * DD + k]; }
                else        { if (k < HH) vi = wih[(l - 1) * 900 + j * HH + k]; }
                if (k < HH) vo = whh[l * 900 + j * HH + k];
            }
            wain[tile][i]  = (_Float16)vi;
            waown[tile][i] = (_Float16)vo;
        }
    }
    // ---- bias as MFMA C-init. D row j2 = 16*tile + 4*qq + r ----
    f32x4 cb[2];
    #pragma unroll
    for (int tile = 0; tile < 2; ++tile)
        #pragma unroll
        for (int r = 0; r < 4; ++r) {
            const int j2 = 16 * tile + 4 * qq + r;
            cb[tile][r] = (j2 < HH) ? bih[l * HH + j2] + bhh[l * HH + j2] : 0.f;
        }
    // FC weights (used by wave 9): k-slice 8*qq + i
    float fcl[8];
    #pragma unroll
    for (int i = 0; i < 8; ++i) {
        const int k = 8 * qq + i;
        fcl[i] = (k < HH) ? fcw[k] : 0.f;
    }
    const float fbv = fcb[0];

    // ---- zero LDS (h(-1) = 0; pads stay 0) ----
    {
        unsigned* z = (unsigned*)sm;
        const int nd = (LL * GRP * WRH + 2 * (LL - 1) * C * GRP * WRH) / 2;
        for (int i = tid; i < nd; i += BLOCKT) z[i] = 0u;
    }
    __syncthreads();

    // ---- wave-0 x prefetch: xb[cc] holds x[b0+n][t=cur*C+cc][8qq..8qq+7] ----
    // float4 index: (b*TT + t)*4 + 2*qq  (only lanes qq<2 carry real data)
    float4 xb[C][2];
    const float4* x4 = (const float4*)x;
    const size_t xbase = (size_t)(b0 + n) * TT * 4;
    if (l == 0 && qq < 2) {
        #pragma unroll
        for (int cc = 0; cc < C; ++cc) {
            xb[cc][0] = x4[xbase + cc * 4 + 2 * qq];
            xb[cc][1] = x4[xbase + cc * 4 + 2 * qq + 1];
        }
    }

    for (int p = 0; p < PH; ++p) {
        const int pt = p - l;         // this wave's chunk index
        const int q  = (p + 1) & 1;   // read parity
        const int wp = p & 1;         // write parity

        if (0 <= pt && pt < TCH) {
            _Float16* ownrow = own + (l * GRP + n) * WRH;
            #pragma unroll
            for (int cc = 0; cc < C; ++cc) {
                // ---- B-in fragment: B[k][n]: n = lane&15, k = 8qq+i ----
                f16x8 bin;
                if (l == 0) {
                    if (qq < 2) {
                        const float4 u = xb[cc][0], v = xb[cc][1];
                        bin[0] = (_Float16)u.x; bin[1] = (_Float16)u.y;
                        bin[2] = (_Float16)u.z; bin[3] = (_Float16)u.w;
                        bin[4] = (_Float16)v.x; bin[5] = (_Float16)v.y;
                        bin[6] = (_Float16)v.z; bin[7] = (_Float16)v.w;
                        if (p + 1 < TCH) {     // refill this slot for next chunk
                            const int tn = (p + 1) * C + cc;
                            xb[cc][0] = x4[xbase + tn * 4 + 2 * qq];
                            xb[cc][1] = x4[xbase + tn * 4 + 2 * qq + 1];
                        }
                    } else {
                        U128 z; z.u = uint4{0u, 0u, 0u, 0u};
                        bin = z.h;
                    }
                } else {
                    U128 r;
                    r.u = *(const uint4*)(act + ACTOFF(q, l - 1, cc) + n * WRH + 8 * qq);
                    bin = r.h;
                }
                // ---- B-own fragment ----
                U128 ro;
                ro.u = *(const uint4*)(ownrow + 8 * qq);
                const f16x8 bown = ro.h;

                // ---- D = Win*in + Wown*own + bias (f32 accum) ----
                f32x4 d0 = __builtin_amdgcn_mfma_f32_16x16x32_f16(wain[0], bin,  cb[0], 0, 0, 0);
                d0       = __builtin_amdgcn_mfma_f32_16x16x32_f16(waown[0], bown, d0,   0, 0, 0);
                f32x4 d1 = __builtin_amdgcn_mfma_f32_16x16x32_f16(wain[1], bin,  cb[1], 0, 0, 0);
                d1       = __builtin_amdgcn_mfma_f32_16x16x32_f16(waown[1], bown, d1,   0, 0, 0);

                // ---- tanh + pack: lane holds batch n, neurons {4qq+r, 16+4qq+r} ----
                f16x4 o0, o1;
                #pragma unroll
                for (int r = 0; r < 4; ++r) {
                    o0[r] = (_Float16)tanh_fast(d0[r]);
                    o1[r] = (_Float16)tanh_fast(d1[r]);
                }

                // ---- write own h (cols 4qq.., 16+4qq..) + handoff to layer l+1 ----
                *(f16x4*)(ownrow + 4 * qq)      = o0;
                *(f16x4*)(ownrow + 16 + 4 * qq) = o1;
                if (l < LL - 1) {
                    _Float16* nx = act + ACTOFF(wp, l, cc) + n * WRH;
                    *(f16x4*)(nx + 4 * qq)      = o0;
                    *(f16x4*)(nx + 16 + 4 * qq) = o1;
                }
            }
        }
        __syncthreads();
    }

    // ---- FC on h_9(T-1), still resident in own[9] ----
    if (l == LL - 1) {
        U128 rh;
        rh.u = *(const uint4*)(own + ((LL - 1) * GRP + n) * WRH + 8 * qq);
        float v = 0.f;
        #pragma unroll
        for (int i = 0; i < 8; ++i) v = fmaf((float)rh.h[i], fcl[i], v);
        v += __shfl_xor(v, 16);      // combine the four qq k-slices
        v += __shfl_xor(v, 32);
        if (qq == 0) out[b0 + n] = v + fbv;
    }
}

extern "C" void kernel_launch(void* const* d_in, const int* in_sizes, int n_in,
                              void* d_out, int out_size, void* d_ws, size_t ws_size,
                              hipStream_t stream) {
    const float* x   = (const float*)d_in[0];
    const float* wi0 = (const float*)d_in[1];
    const float* wih = (const float*)d_in[2];
    const float* whh = (const float*)d_in[3];
    const float* bih = (const float*)d_in[4];
    const float* bhh = (const float*)d_in[5];
    const float* fcw = (const float*)d_in[6];
    const float* fcb = (const float*)d_in[7];
    float* out = (float*)d_out;

    const size_t lds_bytes =
        (size_t)(LL * GRP * WRH + 2 * (LL - 1) * C * GRP * WRH) * sizeof(_Float16); // 104960
    hipFuncSetAttribute((const void*)rnn_mfma,
                        hipFuncAttributeMaxDynamicSharedMemorySize,
                        (int)lds_bytes);

    rnn_mfma<<<1024 / GRP, BLOCKT, lds_bytes, stream>>>(x, wi0, wih, whh,
                                                        bih, bhh, fcw, fcb, out);
}

// Round 8
// 252.631 us; speedup vs baseline: 1.5745x; 1.1080x over previous
//
#include <hip/hip_runtime.h>

#define TT 512
#define DD 16
#define HH 30
#define LL 10
#define C  4                  // timesteps per phase
#define TCH (TT / C)          // 128 chunks
#define PH (TCH + LL - 1)     // 137 phases
#define WRH 40                // halfs per batch-row (80 B): 32 data + pad
#define GRP 16                // batches per block = MFMA N
#define BLOCKT (LL * 64)      // 640 threads, wave = layer

typedef _Float16 f16x8 __attribute__((ext_vector_type(8)));
typedef float    f32x4 __attribute__((ext_vector_type(4)));

union U128 { uint4 u; f16x8 h; };

// act block offset in halfs: [par][destLayer-1][cc] -> [GRP][WRH]
#define ACTOFF(par, lm1, cc) ((((par) * (LL - 1) + (lm1)) * C + (cc)) * (GRP * WRH))

__device__ __forceinline__ float tanh_fast(float x) {
    // tanh(x) = 1 - 2/(exp(2x)+1); saturates correctly at +-inf
    float e = __expf(2.0f * x);
    return 1.0f - 2.0f * __builtin_amdgcn_rcpf(e + 1.0f);
}

// storage k-position <-> natural neuron index permutation.
// kpos(nu) = 8*((nu>>2)&3) + 4*(nu>>4) + (nu&3); nu_of is its inverse.
// Chosen so a lane's D-fragment {16t+4qq+r} lands at positions 8qq+4t+r:
// the MFMA output IS the next step's B-own fragment -- state stays in VGPRs.
__device__ __forceinline__ int nu_of(int k) {
    return 16 * ((k >> 2) & 1) + 4 * (k >> 3) + (k & 3);
}

__global__ __launch_bounds__(BLOCKT) void rnn_mfma2(
    const float* __restrict__ x,   const float* __restrict__ wi0,
    const float* __restrict__ wih, const float* __restrict__ whh,
    const float* __restrict__ bih, const float* __restrict__ bhh,
    const float* __restrict__ fcw, const float* __restrict__ fcb,
    float* __restrict__ out)
{
    extern __shared__ __align__(16) _Float16 act[];  // [2][LL-1][C][GRP][WRH]

    const int tid  = threadIdx.x;
    const int l    = tid >> 6;        // wave == layer
    const int lane = tid & 63;
    const int n    = lane & 15;       // batch-in-group (B col / D col / A m-row)
    const int qq   = lane >> 4;       // k-slice group / D row-group
    const int b0   = blockIdx.x * GRP;

    // ---- A-frags. A[m][k]: m = 16*tile + n (natural neuron out),
    //      k-position kap = 8*qq + i; column = neuron nu_of(kap) (permuted),
    //      except layer-0 input weights (k = x dim, natural). ----
    f16x8 wain[2], waown[2];
    #pragma unroll
    for (int tile = 0; tile < 2; ++tile) {
        const int j = 16 * tile + n;
        #pragma unroll
        for (int i = 0; i < 8; ++i) {
            const int kap = 8 * qq + i;
            const int nu  = nu_of(kap);
            float vi = 0.f, vo = 0.f;
            if (j < HH) {
                if (l == 0) { if (kap < DD) vi = wi0[j * DD + kap]; }
                else        { if (nu  < HH) vi = wih[(l - 1) * 900 + j * HH + nu]; }
                if (nu < HH) vo = whh[l * 900 + j * HH + nu];
            }
            wain[tile][i]  = (_Float16)vi;
            waown[tile][i] = (_Float16)vo;
        }
    }
    // ---- bias as MFMA C-init; D row j2 = 16*tile + 4*qq + r (natural) ----
    f32x4 cb[2];
    #pragma unroll
    for (int tile = 0; tile < 2; ++tile)
        #pragma unroll
        for (int r = 0; r < 4; ++r) {
            const int j2 = 16 * tile + 4 * qq + r;
            cb[tile][r] = (j2 < HH) ? bih[l * HH + j2] + bhh[l * HH + j2] : 0.f;
        }
    // ---- FC weights in this lane's bown layout: i -> neuron nu_of(8qq+i) ----
    float fcl[8];
    #pragma unroll
    for (int i = 0; i < 8; ++i) {
        const int nu = nu_of(8 * qq + i);
        fcl[i] = (nu < HH) ? fcw[nu] : 0.f;
    }
    const float fbv = fcb[0];

    // ---- wave-0 x prefetch: xb[cc] = x[b0+n][t=chunk*C+cc][8qq..8qq+7] ----
    float4 xb[C][2];
    const float4* x4 = (const float4*)x;
    const size_t xbase = (size_t)(b0 + n) * TT * 4;
    if (l == 0 && qq < 2) {
        #pragma unroll
        for (int cc = 0; cc < C; ++cc) {
            xb[cc][0] = x4[xbase + cc * 4 + 2 * qq];
            xb[cc][1] = x4[xbase + cc * 4 + 2 * qq + 1];
        }
    }

    // recurrent state, register-resident: h(-1) = 0
    f16x8 bown;
    #pragma unroll
    for (int i = 0; i < 8; ++i) bown[i] = (_Float16)0.f;

    // no LDS zero-init needed: every act row is written by its producer in
    // phase p-1 before the consumer reads it in phase p (layer 0 uses regs).
    __syncthreads();

    for (int p = 0; p < PH; ++p) {
        const int pt = p - l;         // this wave's chunk index
        const int q  = (p + 1) & 1;   // read parity
        const int wp = p & 1;         // write parity

        if (0 <= pt && pt < TCH) {
            // ---- stage all C input fragments (one lgkm wait, off-chain) ----
            U128 binu[C];
            if (l == 0) {
                #pragma unroll
                for (int cc = 0; cc < C; ++cc) {
                    if (qq < 2) {
                        const float4 u = xb[cc][0], v = xb[cc][1];
                        binu[cc].h[0] = (_Float16)u.x; binu[cc].h[1] = (_Float16)u.y;
                        binu[cc].h[2] = (_Float16)u.z; binu[cc].h[3] = (_Float16)u.w;
                        binu[cc].h[4] = (_Float16)v.x; binu[cc].h[5] = (_Float16)v.y;
                        binu[cc].h[6] = (_Float16)v.z; binu[cc].h[7] = (_Float16)v.w;
                        if (p + 1 < TCH) {   // refill this slot for next chunk
                            const int tn = (p + 1) * C + cc;
                            xb[cc][0] = x4[xbase + tn * 4 + 2 * qq];
                            xb[cc][1] = x4[xbase + tn * 4 + 2 * qq + 1];
                        }
                    } else {
                        binu[cc].u = uint4{0u, 0u, 0u, 0u};
                    }
                }
            } else {
                #pragma unroll
                for (int cc = 0; cc < C; ++cc)
                    binu[cc].u = *(const uint4*)(act + ACTOFF(q, l - 1, cc)
                                                 + n * WRH + 8 * qq);
            }

            // ---- input-side MFMAs for all C steps: independent, issue early ----
            f32x4 dp0[C], dp1[C];
            #pragma unroll
            for (int cc = 0; cc < C; ++cc) {
                dp0[cc] = __builtin_amdgcn_mfma_f32_16x16x32_f16(wain[0], binu[cc].h, cb[0], 0, 0, 0);
                dp1[cc] = __builtin_amdgcn_mfma_f32_16x16x32_f16(wain[1], binu[cc].h, cb[1], 0, 0, 0);
            }

            // ---- serial own-chain: mfma -> tanh -> pack, state in VGPRs ----
            #pragma unroll
            for (int cc = 0; cc < C; ++cc) {
                const f32x4 d0 = __builtin_amdgcn_mfma_f32_16x16x32_f16(waown[0], bown, dp0[cc], 0, 0, 0);
                const f32x4 d1 = __builtin_amdgcn_mfma_f32_16x16x32_f16(waown[1], bown, dp1[cc], 0, 0, 0);
                f16x8 nb;
                #pragma unroll
                for (int r = 0; r < 4; ++r) {
                    nb[r]     = (_Float16)tanh_fast(d0[r]);
                    nb[4 + r] = (_Float16)tanh_fast(d1[r]);
                }
                bown = nb;
                if (l < LL - 1) {    // handoff: contiguous b128, kpos order
                    U128 w; w.h = nb;
                    *(uint4*)(act + ACTOFF(wp, l, cc) + n * WRH + 8 * qq) = w.u;
                }
            }
        }
        __syncthreads();
    }

    // ---- FC on h_9(T-1), register-resident in wave 9's bown ----
    if (l == LL - 1) {
        float v = 0.f;
        #pragma unroll
        for (int i = 0; i < 8; ++i) v = fmaf((float)bown[i], fcl[i], v);
        v += __shfl_xor(v, 16);      // combine the four qq k-slices
        v += __shfl_xor(v, 32);
        if (qq == 0) out[b0 + n] = v + fbv;
    }
}

extern "C" void kernel_launch(void* const* d_in, const int* in_sizes, int n_in,
                              void* d_out, int out_size, void* d_ws, size_t ws_size,
                              hipStream_t stream) {
    const float* x   = (const float*)d_in[0];
    const float* wi0 = (const float*)d_in[1];
    const float* wih = (const float*)d_in[2];
    const float* whh = (const float*)d_in[3];
    const float* bih = (const float*)d_in[4];
    const float* bhh = (const float*)d_in[5];
    const float* fcw = (const float*)d_in[6];
    const float* fcb = (const float*)d_in[7];
    float* out = (float*)d_out;

    const size_t lds_bytes =
        (size_t)(2 * (LL - 1) * C * GRP * WRH) * sizeof(_Float16); // 92160 B
    hipFuncSetAttribute((const void*)rnn_mfma2,
                        hipFuncAttributeMaxDynamicSharedMemorySize,
                        (int)lds_bytes);

    rnn_mfma2<<<1024 / GRP, BLOCKT, lds_bytes, stream>>>(x, wi0, wih, whh,
                                                         bih, bhh, fcw, fcb, out);
}

// Round 9
// 234.380 us; speedup vs baseline: 1.6971x; 1.0779x over previous
//
#include <hip/hip_runtime.h>

#define TT 512
#define DD 16
#define HH 30
#define LL 10
#define C  4                  // timesteps per phase
#define TCH (TT / C)          // 128 chunks
#define PH (TCH + LL - 1)     // 137 phases
#define WRH 40                // halfs per batch-row (80 B): 32 data + pad
#define GRP 16                // batches per block = MFMA N
#define BLOCKT (LL * 64)      // 640 threads, wave = layer

typedef _Float16 f16x8 __attribute__((ext_vector_type(8)));
typedef float    f32x4 __attribute__((ext_vector_type(4)));

union U128 { uint4 u; f16x8 h; };

// act block offset in halfs: [par][destLayer-1][cc] -> [GRP][WRH]
#define ACTOFF(par, lm1, cc) ((((par) * (LL - 1) + (lm1)) * C + (cc)) * (GRP * WRH))

__device__ __forceinline__ float tanh_fast(float x) {
    // tanh(x) = 1 - 2/(2^(2*log2e*x)+1); saturates correctly at +-inf
    float e = __builtin_amdgcn_exp2f(x * 2.88539008177793f);
    return 1.0f - 2.0f * __builtin_amdgcn_rcpf(e + 1.0f);
}

// Raw pipeline barrier: drain LDS ops only (ds_writes visible to the CU),
// do NOT drain vmcnt -- global prefetch stays in flight across phases.
// (__syncthreads would emit s_waitcnt vmcnt(0) and serialize wave-0's
//  x-loads into every phase -- the round-8 stall.)
__device__ __forceinline__ void pipe_barrier() {
    __builtin_amdgcn_sched_barrier(0);
    asm volatile("s_waitcnt lgkmcnt(0)" ::: "memory");
    __builtin_amdgcn_sched_barrier(0);
    __builtin_amdgcn_s_barrier();
    __builtin_amdgcn_sched_barrier(0);
    asm volatile("" ::: "memory");
}

// storage k-position <-> natural neuron index permutation.
// Chosen so a lane's D-fragment {16t+4qq+r} lands at positions 8qq+4t+r:
// the MFMA output IS the next step's B-own fragment -- state stays in VGPRs.
__device__ __forceinline__ int nu_of(int k) {
    return 16 * ((k >> 2) & 1) + 4 * (k >> 3) + (k & 3);
}

__global__ __launch_bounds__(BLOCKT) void rnn_mfma3(
    const float* __restrict__ x,   const float* __restrict__ wi0,
    const float* __restrict__ wih, const float* __restrict__ whh,
    const float* __restrict__ bih, const float* __restrict__ bhh,
    const float* __restrict__ fcw, const float* __restrict__ fcb,
    float* __restrict__ out)
{
    extern __shared__ __align__(16) _Float16 act[];  // [2][LL-1][C][GRP][WRH]

    const int tid  = threadIdx.x;
    const int l    = tid >> 6;        // wave == layer
    const int lane = tid & 63;
    const int n    = lane & 15;       // batch-in-group (B col / D col / A m-row)
    const int qq   = lane >> 4;       // k-slice group / D row-group
    const int b0   = blockIdx.x * GRP;

    // ---- A-frags. A[m][k]: m = 16*tile + n, k-position kap = 8*qq + i;
    //      column = neuron nu_of(kap) (permuted), except layer-0 x (natural).
    f16x8 wain[2], waown[2];
    #pragma unroll
    for (int tile = 0; tile < 2; ++tile) {
        const int j = 16 * tile + n;
        #pragma unroll
        for (int i = 0; i < 8; ++i) {
            const int kap = 8 * qq + i;
            const int nu  = nu_of(kap);
            float vi = 0.f, vo = 0.f;
            if (j < HH) {
                if (l == 0) { if (kap < DD) vi = wi0[j * DD + kap]; }
                else        { if (nu  < HH) vi = wih[(l - 1) * 900 + j * HH + nu]; }
                if (nu < HH) vo = whh[l * 900 + j * HH + nu];
            }
            wain[tile][i]  = (_Float16)vi;
            waown[tile][i] = (_Float16)vo;
        }
    }
    // ---- bias as MFMA C-init; D row j2 = 16*tile + 4*qq + r (natural) ----
    f32x4 cb[2];
    #pragma unroll
    for (int tile = 0; tile < 2; ++tile)
        #pragma unroll
        for (int r = 0; r < 4; ++r) {
            const int j2 = 16 * tile + 4 * qq + r;
            cb[tile][r] = (j2 < HH) ? bih[l * HH + j2] + bhh[l * HH + j2] : 0.f;
        }
    // ---- FC weights in this lane's bown layout: i -> neuron nu_of(8qq+i) ----
    float fcl[8];
    #pragma unroll
    for (int i = 0; i < 8; ++i) {
        const int nu = nu_of(8 * qq + i);
        fcl[i] = (nu < HH) ? fcw[nu] : 0.f;
    }
    const float fbv = fcb[0];

    // ---- wave-0 x prefetch: xb[cc] = x[b0+n][t=chunk*C+cc][8qq..8qq+7] ----
    float4 xb[C][2];
    const float4* x4 = (const float4*)x;
    const size_t xbase = (size_t)(b0 + n) * TT * 4;
    if (l == 0 && qq < 2) {
        #pragma unroll
        for (int cc = 0; cc < C; ++cc) {
            xb[cc][0] = x4[xbase + cc * 4 + 2 * qq];
            xb[cc][1] = x4[xbase + cc * 4 + 2 * qq + 1];
        }
    }

    // recurrent state, register-resident: h(-1) = 0
    f16x8 bown;
    #pragma unroll
    for (int i = 0; i < 8; ++i) bown[i] = (_Float16)0.f;

    __syncthreads();   // once, pre-loop (no LDS init needed; phase alignment)

    for (int p = 0; p < PH; ++p) {
        const int pt = p - l;         // this wave's chunk index
        const int q  = (p + 1) & 1;   // read parity
        const int wp = p & 1;         // write parity

        if (0 <= pt && pt < TCH) {
            // ---- stage all C input fragments (one lgkm wait, off-chain) ----
            U128 binu[C];
            if (l == 0) {
                #pragma unroll
                for (int cc = 0; cc < C; ++cc) {
                    if (qq < 2) {
                        const float4 u = xb[cc][0], v = xb[cc][1];
                        binu[cc].h[0] = (_Float16)u.x; binu[cc].h[1] = (_Float16)u.y;
                        binu[cc].h[2] = (_Float16)u.z; binu[cc].h[3] = (_Float16)u.w;
                        binu[cc].h[4] = (_Float16)v.x; binu[cc].h[5] = (_Float16)v.y;
                        binu[cc].h[6] = (_Float16)v.z; binu[cc].h[7] = (_Float16)v.w;
                        if (p + 1 < TCH) {   // refill this slot for next chunk
                            const int tn = (p + 1) * C + cc;
                            xb[cc][0] = x4[xbase + tn * 4 + 2 * qq];
                            xb[cc][1] = x4[xbase + tn * 4 + 2 * qq + 1];
                        }
                    } else {
                        binu[cc].u = uint4{0u, 0u, 0u, 0u};
                    }
                }
            } else {
                #pragma unroll
                for (int cc = 0; cc < C; ++cc)
                    binu[cc].u = *(const uint4*)(act + ACTOFF(q, l - 1, cc)
                                                 + n * WRH + 8 * qq);
            }

            // ---- input-side MFMAs for all C steps: independent, issue early ----
            f32x4 dp0[C], dp1[C];
            #pragma unroll
            for (int cc = 0; cc < C; ++cc) {
                dp0[cc] = __builtin_amdgcn_mfma_f32_16x16x32_f16(wain[0], binu[cc].h, cb[0], 0, 0, 0);
                dp1[cc] = __builtin_amdgcn_mfma_f32_16x16x32_f16(wain[1], binu[cc].h, cb[1], 0, 0, 0);
            }

            // ---- serial own-chain: mfma -> tanh -> pack, state in VGPRs ----
            #pragma unroll
            for (int cc = 0; cc < C; ++cc) {
                const f32x4 d0 = __builtin_amdgcn_mfma_f32_16x16x32_f16(waown[0], bown, dp0[cc], 0, 0, 0);
                const f32x4 d1 = __builtin_amdgcn_mfma_f32_16x16x32_f16(waown[1], bown, dp1[cc], 0, 0, 0);
                f16x8 nb;
                #pragma unroll
                for (int r = 0; r < 4; ++r) {
                    nb[r]     = (_Float16)tanh_fast(d0[r]);
                    nb[4 + r] = (_Float16)tanh_fast(d1[r]);
                }
                bown = nb;
                if (l < LL - 1) {    // handoff: contiguous b128, kpos order
                    U128 w; w.h = nb;
                    *(uint4*)(act + ACTOFF(wp, l, cc) + n * WRH + 8 * qq) = w.u;
                }
            }
        }
        pipe_barrier();               // lgkm drain only; vmem stays in flight
    }

    // ---- FC on h_9(T-1), register-resident in wave 9's bown ----
    if (l == LL - 1) {
        float v = 0.f;
        #pragma unroll
        for (int i = 0; i < 8; ++i) v = fmaf((float)bown[i], fcl[i], v);
        v += __shfl_xor(v, 16);      // combine the four qq k-slices
        v += __shfl_xor(v, 32);
        if (qq == 0) out[b0 + n] = v + fbv;
    }
}

extern "C" void kernel_launch(void* const* d_in, const int* in_sizes, int n_in,
                              void* d_out, int out_size, void* d_ws, size_t ws_size,
                              hipStream_t stream) {
    const float* x   = (const float*)d_in[0];
    const float* wi0 = (const float*)d_in[1];
    const float* wih = (const float*)d_in[2];
    const float* whh = (const float*)d_in[3];
    const float* bih = (const float*)d_in[4];
    const float* bhh = (const float*)d_in[5];
    const float* fcw = (const float*)d_in[6];
    const float* fcb = (const float*)d_in[7];
    float* out = (float*)d_out;

    const size_t lds_bytes =
        (size_t)(2 * (LL - 1) * C * GRP * WRH) * sizeof(_Float16); // 92160 B
    hipFuncSetAttribute((const void*)rnn_mfma3,
                        hipFuncAttributeMaxDynamicSharedMemorySize,
                        (int)lds_bytes);

    rnn_mfma3<<<1024 / GRP, BLOCKT, lds_bytes, stream>>>(x, wi0, wih, whh,
                                                         bih, bhh, fcw, fcb, out);
}